// Round 16
// baseline (120.295 us; speedup 1.0000x reference)
//
#include <hip/hip_runtime.h>

#define B_ 8
#define N_ 1024
#define D_ 768
#define H_ 12
#define HD_ 64

#define LOG2E 1.4426950408889634f

typedef __attribute__((ext_vector_type(8))) short bf16x8;
typedef __attribute__((ext_vector_type(4))) short short4_t;
typedef __attribute__((ext_vector_type(4))) float f32x4;
typedef __attribute__((ext_vector_type(16))) float f32x16;
typedef unsigned int u32;

__device__ __forceinline__ short f2bf(float f) {
  union { float f; unsigned u; } v; v.f = f;
  unsigned u = v.u;
  unsigned r = u + 0x7fffu + ((u >> 16) & 1u);
  return (short)(r >> 16);
}
__device__ __forceinline__ float bf2f(short s) {
  union { unsigned u; float f; } v;
  v.u = ((unsigned)(unsigned short)s) << 16;
  return v.f;
}
// packed bf16 pair: low = cvt(a), high = cvt(b); RNE rounding
__device__ __forceinline__ u32 cvtpk(float a, float b) {
  u32 r;
  asm("v_cvt_pk_bf16_f32 %0, %1, %2" : "=v"(r) : "v"(a), "v"(b));
  return r;
}
// swap: a' = (lo: a.lo, hi: b.lo) ; b' = (lo: a.hi, hi: b.hi)
__device__ __forceinline__ void pl32swap(u32& a, u32& b) {
  asm("v_permlane32_swap_b32 %0, %1" : "+v"(a), "+v"(b));
}

// direct global -> LDS DMA, 16B per lane. LDS dest = wave-uniform base + lane*16.
__device__ __forceinline__ void gload_lds16(const void* g, void* l) {
  __builtin_amdgcn_global_load_lds((const __attribute__((address_space(1))) u32*)g,
                                   (__attribute__((address_space(3))) u32*)l, 16, 0, 0);
}

// ---------------- cvt_w: W f32->bf16 transposed (Wt[n][k] = W[k][n]) ----------------
__global__ __launch_bounds__(256)
void cvt_kernel(const float* __restrict__ Wq, const float* __restrict__ Wk,
                const float* __restrict__ Wv, short* __restrict__ Wt3) {
  const int bid = blockIdx.x;
  const int tid = threadIdx.x;
  const int z = bid / 576;
  const int rem = bid % 576;
  const int bx = rem % 24, by = rem / 24;
  const float* W = z == 0 ? Wq : (z == 1 ? Wk : Wv);
  short* O = Wt3 + (size_t)z * D_ * D_;
  __shared__ float t[32][33];
  const int n0 = bx * 32, k0 = by * 32;
  const int tx = tid & 31, ty = tid >> 5;
#pragma unroll
  for (int j = 0; j < 4; j++)
    t[ty + 8 * j][tx] = W[(size_t)(k0 + ty + 8 * j) * D_ + n0 + tx];
  __syncthreads();
#pragma unroll
  for (int j = 0; j < 4; j++)
    O[(size_t)(n0 + ty + 8 * j) * D_ + k0 + tx] = f2bf(t[tx][ty + 8 * j]);
}

// ---------------- fused GEMM + madj (independent work, concurrent blocks) ----------------
// blocks [0,1152): QKV GEMM (dispatched first; MFMA/LDS-bound); A read f32-direct + cvt
// blocks [1152,3200): madj fragments (HBM-bound, fills remaining bandwidth)
__global__ __launch_bounds__(256, 4)
void gemm_madj_kernel(const float* __restrict__ X, const short* __restrict__ Wt3,
                      const float* __restrict__ bq, const float* __restrict__ bk,
                      const float* __restrict__ bv, short* __restrict__ QKV,
                      const float* __restrict__ adj, const float* __restrict__ beta_p,
                      short* __restrict__ madjF) {
  __shared__ __align__(16) char smem[32768];
  const int bid = blockIdx.x;
  const int tid = threadIdx.x;

  if (bid < 1152) {
    // ================= GEMM: C = X @ W + b =================
    const int z = bid / 384;
    const int n0 = ((bid >> 6) % 6) * 128;
    const int m0 = (bid & 63) * 128;
    const short* Wt = Wt3 + (size_t)z * D_ * D_;
    const float* bias = z == 0 ? bq : (z == 1 ? bk : bv);
    short* C = QKV + (size_t)z * (B_ * N_) * D_;
    const float alpha = (z == 0) ? 0.125f * LOG2E : 1.0f;

    const int lane = tid & 63;
    const int wid = tid >> 6;
    const int wr = (wid >> 1) * 64;
    const int wc = (wid & 1) * 64;
    const int l15 = lane & 15;
    const int lg = lane >> 4;

    short* At = (short*)smem;          // [2][128][32]
    short* Bt = (short*)smem + 8192;   // [2][128][32]

    f32x4 acc[4][4];
#pragma unroll
    for (int m = 0; m < 4; m++)
#pragma unroll
      for (int n = 0; n < 4; n++)
        acc[m][n] = (f32x4){0.f, 0.f, 0.f, 0.f};

    const int srow_l = lane >> 2;
    const int sc8 = (((lane & 3) ^ ((lane >> 2) & 3)) * 8);
    const float* ag = X + (size_t)(m0 + wid * 16 + srow_l) * D_ + sc8;   // f32 source
    const short* bg = Wt + (size_t)(n0 + wid * 16 + srow_l) * D_ + sc8;

    // B: DMA. A: f32 loads -> cvt_pk -> ds_write_b128 (same phys layout as DMA would give).
    auto stageB = [&](int bi, int k0) {
#pragma unroll
      for (int p = 0; p < 2; p++)
        gload_lds16(bg + (size_t)(64 * p) * D_ + k0, Bt + bi * 4096 + (wid + 4 * p) * 512);
    };
    auto stageA = [&](int bi, int k0) {
      float4 a0[2], a1[2];
#pragma unroll
      for (int p = 0; p < 2; p++) {
        const float* src = ag + (size_t)(64 * p) * D_ + k0;
        a0[p] = *(const float4*)src;
        a1[p] = *(const float4*)(src + 4);
      }
#pragma unroll
      for (int p = 0; p < 2; p++) {
        union { u32 u[4]; bf16x8 v; } o;
        o.u[0] = cvtpk(a0[p].x, a0[p].y);
        o.u[1] = cvtpk(a0[p].z, a0[p].w);
        o.u[2] = cvtpk(a1[p].x, a1[p].y);
        o.u[3] = cvtpk(a1[p].z, a1[p].w);
        *(bf16x8*)(At + bi * 4096 + (wid + 4 * p) * 512 + lane * 8) = o.v;
      }
    };

    stageB(0, 0);
    stageA(0, 0);
    for (int k0 = 0; k0 < D_; k0 += 32) {
      const int cur = (k0 >> 5) & 1;
      __syncthreads();                       // drains vm+lgkm: buf[cur] ready
      if (k0 + 32 < D_) {
        stageB(cur ^ 1, k0 + 32);
        stageA(cur ^ 1, k0 + 32);
      }

      bf16x8 af[4], bfr[4];
#pragma unroll
      for (int m = 0; m < 4; m++) {
        const int row = wr + m * 16 + l15;
        af[m] = *(const bf16x8*)(At + cur * 4096 + row * 32 + (lg ^ (l15 & 3)) * 8);
      }
#pragma unroll
      for (int n = 0; n < 4; n++) {
        const int row = wc + n * 16 + l15;
        bfr[n] = *(const bf16x8*)(Bt + cur * 4096 + row * 32 + (lg ^ (l15 & 3)) * 8);
      }
#pragma unroll
      for (int m = 0; m < 4; m++)
#pragma unroll
        for (int n = 0; n < 4; n++)
          acc[m][n] = __builtin_amdgcn_mfma_f32_16x16x32_bf16(af[m], bfr[n], acc[m][n], 0, 0, 0);
    }

    if (z == 2) {
      // V written TRANSPOSED per head: VTg[((b*12+h)*64+d)][n]
#pragma unroll
      for (int n = 0; n < 4; n++) {
        const int col = n0 + wc + n * 16 + l15;
        const float bval = bias[col];
        const int hh = col >> 6, dd = col & 63;
#pragma unroll
        for (int m = 0; m < 4; m++) {
          const int row = m0 + wr + m * 16 + 4 * lg;
          const int bb = row >> 10, nn = row & 1023;
          short4_t o;
#pragma unroll
          for (int r = 0; r < 4; r++) o[r] = f2bf(acc[m][n][r] + bval);
          *(short4_t*)&C[(((size_t)bb * H_ + hh) * HD_ + dd) * N_ + nn] = o;
        }
      }
    } else {
#pragma unroll
      for (int n = 0; n < 4; n++) {
        const int col = n0 + wc + n * 16 + l15;
        const float bval = bias[col];
#pragma unroll
        for (int m = 0; m < 4; m++) {
#pragma unroll
          for (int r = 0; r < 4; r++) {
            const int row = m0 + wr + m * 16 + 4 * lg + r;
            C[(size_t)row * D_ + col] = f2bf((acc[m][n][r] + bval) * alpha);
          }
        }
      }
    }
  } else {
    // ================= madj: fused mask/beta/log2e, 32x32 S^T C-fragment order =================
    const int j = bid - 1152;
    const int b = j >> 8;
    const int rr = j & 255;
    const int qt64 = rr >> 4, kt = rr & 15;   // 64-q-row slab
    const float b2 = beta_p[0] * LOG2E;
    const float MASKV = -9.0e15f * LOG2E;

    float* Lt = (float*)smem;                  // [64][68]
    {
      const int row = tid >> 2, cs = (tid & 3) * 16;
      const float* ap = adj + ((size_t)b * N_ + qt64 * 64 + row) * (size_t)N_ + kt * 64 + cs;
#pragma unroll
      for (int jj = 0; jj < 4; jj++)
        *(float4*)(Lt + row * 68 + cs + 4 * jj) = *(const float4*)(ap + 4 * jj);
    }
    __syncthreads();

    const int a = tid >> 1, cb = tid & 1;
    const int lane_att = a & 63;
    const int l31 = lane_att & 31, hia = lane_att >> 5;
    const int q_local = 32 * (a >> 6) + l31;

    short vals[16];
#pragma unroll
    for (int t = 0; t < 4; t++) {
      float4 a4 = *(const float4*)(Lt + q_local * 68 + 32 * cb + 8 * t + 4 * hia);
      float av[4] = {a4.x, a4.y, a4.z, a4.w};
#pragma unroll
      for (int r2 = 0; r2 < 4; r2++) {
        float av_ = av[r2];
        vals[4 * t + r2] = f2bf((av_ > 0.f) ? b2 * av_ : MASKV);
      }
    }
    short* o = madjF + ((size_t)((b * 8 + (qt64 >> 1)) * 16 + kt)) * 8192 +
               (qt64 & 1) * 4096 + tid * 16;
    bf16x8 lo, hi;
#pragma unroll
    for (int jj = 0; jj < 8; jj++) { lo[jj] = vals[jj]; hi[jj] = vals[8 + jj]; }
    *(bf16x8*)o = lo;
    *(bf16x8*)(o + 8) = hi;
  }
}

// ---- attn helper macros (flat code, constant-indexed arrays only) ----
// QK half: 4 chained MFMAs, C-init from two bf16x8 madj fragments
#define QK_HALF(SREG, K0, ROWOFF, MJA, MJB)                                    \
  {                                                                            \
    f32x16 c_;                                                                 \
    _Pragma("unroll") for (int r_ = 0; r_ < 8; r_++) c_[r_] = bf2f(MJA[r_]);   \
    _Pragma("unroll") for (int r_ = 0; r_ < 8; r_++) c_[8 + r_] = bf2f(MJB[r_]);\
    _Pragma("unroll") for (int s_ = 0; s_ < 4; s_++) {                         \
      bf16x8 kf_ = *(const bf16x8*)((K0) + ((ROWOFF) + l31) * 64 +             \
                                    (((2 * s_ + hi) ^ swz) * 8));              \
      c_ = __builtin_amdgcn_mfma_f32_32x32x16_bf16(kf_, qf[s_], c_, 0, 0, 0);  \
    }                                                                          \
    SREG = c_;                                                                 \
  }

// pack half: 16 exp2 + row-sum contrib + 8 cvtpk + 4 permlane -> FW[OFF..OFF+7]
#define PACK_HALF(SREG, FW, OFF)                                               \
  {                                                                            \
    _Pragma("unroll") for (int r_ = 0; r_ < 16; r_++) {                        \
      SREG[r_] = __builtin_exp2f(SREG[r_]); ps += SREG[r_];                    \
    }                                                                          \
    u32 wv_[8];                                                                \
    _Pragma("unroll") for (int c_ = 0; c_ < 8; c_++)                           \
      wv_[c_] = cvtpk(SREG[2 * c_], SREG[2 * c_ + 1]);                         \
    pl32swap(wv_[0], wv_[2]); FW[(OFF) + 0] = wv_[0]; FW[(OFF) + 2] = wv_[2];  \
    pl32swap(wv_[1], wv_[3]); FW[(OFF) + 1] = wv_[1]; FW[(OFF) + 3] = wv_[3];  \
    pl32swap(wv_[4], wv_[6]); FW[(OFF) + 4] = wv_[4]; FW[(OFF) + 6] = wv_[6];  \
    pl32swap(wv_[5], wv_[7]); FW[(OFF) + 5] = wv_[5]; FW[(OFF) + 7] = wv_[7];  \
  }

// PV half: 2 k-slices (KS0, KS0+1), 4 MFMAs into acc0/acc1
#define PV_HALF(FW, V0, KS0)                                                   \
  _Pragma("unroll") for (int ks_ = (KS0); ks_ < (KS0) + 2; ks_++) {            \
    union { u32 u[4]; bf16x8 v; } pu_;                                         \
    pu_.u[0] = FW[4 * ks_];     pu_.u[1] = FW[4 * ks_ + 1];                    \
    pu_.u[2] = FW[4 * ks_ + 2]; pu_.u[3] = FW[4 * ks_ + 3];                    \
    bf16x8 vf0_ = *(const bf16x8*)((V0) + l31 * 64 + (((2 * ks_ + hi) ^ swz) * 8)); \
    bf16x8 vf1_ = *(const bf16x8*)((V0) + (32 + l31) * 64 + (((2 * ks_ + hi) ^ swz) * 8)); \
    acc0 = __builtin_amdgcn_mfma_f32_32x32x16_bf16(vf0_, pu_.v, acc0, 0, 0, 0);\
    acc1 = __builtin_amdgcn_mfma_f32_32x32x16_bf16(vf1_, pu_.v, acc1, 0, 0, 0);\
  }

// ---------------- flash attention: 32x32 MFMA, no-max softmax, 1-tile-lookbehind PV -------
// Per tile t: QK(t) [MFMA] + PV(t-1) [MFMA, indep] + pack(t) [VALU] interleave.
// Cross-tile state: packed P fragments fwP[16] (u32) only. K 2-buf, V 3-buf in LDS.
// l_ accumulates per-lane half-row sums; single cross-half shfl reduce at the end.
__global__ __launch_bounds__(256, 3)
void attn_kernel(const short* __restrict__ QKV, const short* __restrict__ madjF,
                 float* __restrict__ out) {
  const short* Qb = QKV;
  const short* Kb = QKV + (size_t)(B_ * N_) * D_;
  const short* VTg = QKV + 2 * (size_t)(B_ * N_) * D_;   // per-head transposed V

  // 768 blocks = 8 XCD x 96; batch b pinned to XCD b
  const int wg = blockIdx.x;
  const int b = wg & 7;
  const int rem = wg >> 3;        // 0..95
  const int h = rem >> 3;         // 0..11
  const int qt = rem & 7;         // 0..7 (128-row q tiles)

  const int tid = threadIdx.x;
  const int lane = tid & 63;
  const int w = tid >> 6;         // wave 0..3: q rows [32w, 32w+32)
  const int l31 = lane & 31;
  const int hi = lane >> 5;
  const int swz = lane & 7;       // LDS chunk swizzle key

  const int q0 = qt * 128;
  const size_t seq0 = (size_t)b * N_;
  const int hc = h * HD_;

  __shared__ short Kt[2][64][64];    // row k', phys 16B-chunk p holds logical chunk p^(k'&7)
  __shared__ short VTt[3][64][64];   // row d, same swizzle; triple-buffered

  // Q fragments: lane holds Q[q=q0+32w+l31][d = 16s + 8hi + j]
  bf16x8 qf[4];
  {
    const short* qp = Qb + (seq0 + q0 + 32 * w + l31) * (size_t)D_ + hc + 8 * hi;
#pragma unroll
    for (int s = 0; s < 4; s++) qf[s] = *(const bf16x8*)(qp + 16 * s);
  }

  f32x16 acc0 = {}, acc1 = {};     // PV acc: D[d][q], d-tiles 0,1
  float l_ = 0.f;

  // staging: each wave stages 16 rows of K and 16 rows of V^T per tile (2 DMA each)
  const int srow = 16 * w + (lane >> 3);
  const int sc8 = ((lane & 7) ^ (lane >> 3)) * 8;
  const short* kg = Kb + (seq0 + srow) * (size_t)D_ + hc + sc8;
  const short* vg = VTg + ((size_t)(b * H_ + h) * HD_ + srow) * N_ + sc8;
  const short* mg = madjF + ((size_t)(b * 8 + qt) * 16) * 8192 + (w * 64 + lane) * 32;

  bf16x8 mjc[4], mjn[4];
  u32 fwP[16], fwN[16];

  // prologue: stage tiles 0,1; full QK+pack of tile 0 (no PV yet)
  {
    gload_lds16(kg, ((short*)Kt[0]) + (size_t)w * 1024);
    gload_lds16(kg + 8 * (size_t)D_, ((short*)Kt[0]) + (size_t)w * 1024 + 512);
    gload_lds16(vg, ((short*)VTt[0]) + (size_t)w * 1024);
    gload_lds16(vg + 8 * (size_t)N_, ((short*)VTt[0]) + (size_t)w * 1024 + 512);
#pragma unroll
    for (int j = 0; j < 4; j++) mjc[j] = *(const bf16x8*)(mg + 8 * j);
    __syncthreads();
    gload_lds16(kg + (size_t)64 * D_, ((short*)Kt[1]) + (size_t)w * 1024);
    gload_lds16(kg + (size_t)72 * D_, ((short*)Kt[1]) + (size_t)w * 1024 + 512);
    gload_lds16(vg + 64, ((short*)VTt[1]) + (size_t)w * 1024);
    gload_lds16(vg + 64 + 8 * (size_t)N_, ((short*)VTt[1]) + (size_t)w * 1024 + 512);
#pragma unroll
    for (int j = 0; j < 4; j++) mjn[j] = *(const bf16x8*)(mg + 8192 + 8 * j);

    float ps = 0.f;
    f32x16 s0, s1;
    const short* K0 = (const short*)Kt[0];
    QK_HALF(s0, K0, 0, mjc[0], mjc[1]);
    PACK_HALF(s0, fwP, 0);
    QK_HALF(s1, K0, 32, mjc[2], mjc[3]);
    PACK_HALF(s1, fwP, 8);
    l_ += ps;
#pragma unroll
    for (int j = 0; j < 4; j++) mjc[j] = mjn[j];
  }

  // main loop: tiles 1..15.  QK(t) + PV(t-1) + pack(t).
  int vprev = 0;   // (t-1)%3
  int vstage = 2;  // (t+1)%3
  for (int t = 1; t < 16; t++) {
    __syncthreads();                 // tile t staged; prev-tile LDS reads done
    if (t < 15) {
      const int k0 = (t + 1) * 64;
      gload_lds16(kg + (size_t)k0 * D_, ((short*)Kt[(t + 1) & 1]) + (size_t)w * 1024);
      gload_lds16(kg + (size_t)(k0 + 8) * D_, ((short*)Kt[(t + 1) & 1]) + (size_t)w * 1024 + 512);
      gload_lds16(vg + k0, ((short*)VTt[vstage]) + (size_t)w * 1024);
      gload_lds16(vg + k0 + 8 * (size_t)N_, ((short*)VTt[vstage]) + (size_t)w * 1024 + 512);
#pragma unroll
      for (int j = 0; j < 4; j++)
        mjn[j] = *(const bf16x8*)(mg + (size_t)(t + 1) * 8192 + 8 * j);
    }

    const short* K0 = (const short*)Kt[t & 1];
    const short* V0 = (const short*)VTt[vprev];
    float ps = 0.f;
    f32x16 s0, s1;

    QK_HALF(s0, K0, 0, mjc[0], mjc[1]);   // MFMA chain A
    PV_HALF(fwP, V0, 0);                  // MFMA, independent of A — fills pipe
    PACK_HALF(s0, fwN, 0);                // VALU, dep A — overlaps PV MFMAs
    QK_HALF(s1, K0, 32, mjc[2], mjc[3]);  // MFMA chain B
    PV_HALF(fwP, V0, 2);                  // MFMA, independent
    PACK_HALF(s1, fwN, 8);                // VALU, dep B
    l_ += ps;

#pragma unroll
    for (int i = 0; i < 16; i++) fwP[i] = fwN[i];
#pragma unroll
    for (int j = 0; j < 4; j++) mjc[j] = mjn[j];
    vprev = (vprev == 2) ? 0 : vprev + 1;
    vstage = (vstage == 2) ? 0 : vstage + 1;
  }

  // tail: PV of tile 15 (V buffer = 15%3 = vprev after loop)
  {
    const short* V0 = (const short*)VTt[vprev];
    PV_HALF(fwP, V0, 0);
    PV_HALF(fwP, V0, 2);
  }

  // cross-half reduce of l (each lane held only its hi-half k-sums), then normalize
  l_ += __shfl_xor(l_, 32);
  const float invl = 1.f / l_;
  float* orow = out + (seq0 + q0 + 32 * w + l31) * (size_t)D_ + hc;
#pragma unroll
  for (int t = 0; t < 4; t++) {
    float4 o0, o1;
    o0.x = acc0[4 * t] * invl;     o0.y = acc0[4 * t + 1] * invl;
    o0.z = acc0[4 * t + 2] * invl; o0.w = acc0[4 * t + 3] * invl;
    o1.x = acc1[4 * t] * invl;     o1.y = acc1[4 * t + 1] * invl;
    o1.z = acc1[4 * t + 2] * invl; o1.w = acc1[4 * t + 3] * invl;
    *(float4*)(orow + 8 * t + 4 * hi) = o0;
    *(float4*)(orow + 8 * t + 4 * hi + 32) = o1;
  }
}

extern "C" void kernel_launch(void* const* d_in, const int* in_sizes, int n_in,
                              void* d_out, int out_size, void* d_ws, size_t ws_size,
                              hipStream_t stream) {
  const float* X    = (const float*)d_in[0];
  const float* adj  = (const float*)d_in[1];
  const float* Wq   = (const float*)d_in[2];
  const float* bq   = (const float*)d_in[3];
  const float* Wk   = (const float*)d_in[4];
  const float* bk   = (const float*)d_in[5];
  const float* Wv   = (const float*)d_in[6];
  const float* bv   = (const float*)d_in[7];
  const float* beta = (const float*)d_in[8];
  float* out = (float*)d_out;

  // workspace (shorts): Wt3 | QKV | madjF  (V slab of QKV holds per-head transposed V)
  short* Wt3   = (short*)d_ws;
  short* QKV   = Wt3 + 3 * (size_t)D_ * D_;
  short* madjF = QKV + 3 * (size_t)(B_ * N_) * D_;

  cvt_kernel<<<dim3(1728), 256, 0, stream>>>(Wq, Wk, Wv, Wt3);
  gemm_madj_kernel<<<dim3(3200), 256, 0, stream>>>(X, Wt3, bq, bk, bv, QKV, adj, beta, madjF);
  attn_kernel<<<dim3(768), 256, 0, stream>>>(QKV, madjF, out);
}

// Round 17
// 108.355 us; speedup vs baseline: 1.1102x; 1.1102x over previous
//
#include <hip/hip_runtime.h>

#define B_ 8
#define N_ 1024
#define D_ 768
#define H_ 12
#define HD_ 64

#define LOG2E 1.4426950408889634f

typedef __attribute__((ext_vector_type(8))) short bf16x8;
typedef __attribute__((ext_vector_type(4))) short short4_t;
typedef __attribute__((ext_vector_type(4))) float f32x4;
typedef __attribute__((ext_vector_type(16))) float f32x16;
typedef unsigned int u32;

__device__ __forceinline__ short f2bf(float f) {
  union { float f; unsigned u; } v; v.f = f;
  unsigned u = v.u;
  unsigned r = u + 0x7fffu + ((u >> 16) & 1u);
  return (short)(r >> 16);
}
__device__ __forceinline__ float bf2f(short s) {
  union { unsigned u; float f; } v;
  v.u = ((unsigned)(unsigned short)s) << 16;
  return v.f;
}
// packed bf16 pair: low = cvt(a), high = cvt(b); RNE rounding
__device__ __forceinline__ u32 cvtpk(float a, float b) {
  u32 r;
  asm("v_cvt_pk_bf16_f32 %0, %1, %2" : "=v"(r) : "v"(a), "v"(b));
  return r;
}
// swap: a' = (lo: a.lo, hi: b.lo) ; b' = (lo: a.hi, hi: b.hi)
__device__ __forceinline__ void pl32swap(u32& a, u32& b) {
  asm("v_permlane32_swap_b32 %0, %1" : "+v"(a), "+v"(b));
}

// direct global -> LDS DMA, 16B per lane. LDS dest = wave-uniform base + lane*16.
__device__ __forceinline__ void gload_lds16(const void* g, void* l) {
  __builtin_amdgcn_global_load_lds((const __attribute__((address_space(1))) u32*)g,
                                   (__attribute__((address_space(3))) u32*)l, 16, 0, 0);
}

// ---------------- cvt: X f32->bf16 | W f32->bf16 transposed ----------------
// blocks [0,3072): cvt_x ; [3072,4800): cvt_w
__global__ __launch_bounds__(256)
void cvt_kernel(const float* __restrict__ X, short* __restrict__ Xb,
                const float* __restrict__ Wq, const float* __restrict__ Wk,
                const float* __restrict__ Wv, short* __restrict__ Wt3) {
  const int bid = blockIdx.x;
  const int tid = threadIdx.x;

  if (bid < 3072) {
    int i = (bid * 256 + tid) * 8;
    float4 a = *(const float4*)(X + i);
    float4 b = *(const float4*)(X + i + 4);
    bf16x8 o;
    o[0] = f2bf(a.x); o[1] = f2bf(a.y); o[2] = f2bf(a.z); o[3] = f2bf(a.w);
    o[4] = f2bf(b.x); o[5] = f2bf(b.y); o[6] = f2bf(b.z); o[7] = f2bf(b.w);
    *(bf16x8*)(Xb + i) = o;
  } else {
    const int i = bid - 3072;
    const int z = i / 576;
    const int rem = i % 576;
    const int bx = rem % 24, by = rem / 24;
    const float* W = z == 0 ? Wq : (z == 1 ? Wk : Wv);
    short* O = Wt3 + (size_t)z * D_ * D_;
    __shared__ float t[32][33];
    const int n0 = bx * 32, k0 = by * 32;
    const int tx = tid & 31, ty = tid >> 5;
#pragma unroll
    for (int j = 0; j < 4; j++)
      t[ty + 8 * j][tx] = W[(size_t)(k0 + ty + 8 * j) * D_ + n0 + tx];
    __syncthreads();
#pragma unroll
    for (int j = 0; j < 4; j++)
      O[(size_t)(n0 + ty + 8 * j) * D_ + k0 + tx] = f2bf(t[tx][ty + 8 * j]);
  }
}

// ---------------- fused GEMM + madj (independent work, concurrent blocks) ----------------
// blocks [0,1152): QKV GEMM (dispatched first; MFMA/LDS-bound)
// blocks [1152,3200): madj fragments (HBM-bound, fills remaining bandwidth)
__global__ __launch_bounds__(256, 4)
void gemm_madj_kernel(const short* __restrict__ Xb, const short* __restrict__ Wt3,
                      const float* __restrict__ bq, const float* __restrict__ bk,
                      const float* __restrict__ bv, short* __restrict__ QKV,
                      const float* __restrict__ adj, const float* __restrict__ beta_p,
                      short* __restrict__ madjF) {
  __shared__ __align__(16) char smem[32768];
  const int bid = blockIdx.x;
  const int tid = threadIdx.x;

  if (bid < 1152) {
    // ================= GEMM: C = X @ W + b =================
    const int z = bid / 384;
    const int n0 = ((bid >> 6) % 6) * 128;
    const int m0 = (bid & 63) * 128;
    const short* Wt = Wt3 + (size_t)z * D_ * D_;
    const float* bias = z == 0 ? bq : (z == 1 ? bk : bv);
    short* C = QKV + (size_t)z * (B_ * N_) * D_;
    const float alpha = (z == 0) ? 0.125f * LOG2E : 1.0f;

    const int lane = tid & 63;
    const int wid = tid >> 6;
    const int wr = (wid >> 1) * 64;
    const int wc = (wid & 1) * 64;
    const int l15 = lane & 15;
    const int lg = lane >> 4;

    short* At = (short*)smem;          // [2][128][32]
    short* Bt = (short*)smem + 8192;   // [2][128][32]

    f32x4 acc[4][4];
#pragma unroll
    for (int m = 0; m < 4; m++)
#pragma unroll
      for (int n = 0; n < 4; n++)
        acc[m][n] = (f32x4){0.f, 0.f, 0.f, 0.f};

    const int srow_l = lane >> 2;
    const int sc8 = (((lane & 3) ^ ((lane >> 2) & 3)) * 8);
    const short* ag = Xb + (size_t)(m0 + wid * 16 + srow_l) * D_ + sc8;
    const short* bg = Wt + (size_t)(n0 + wid * 16 + srow_l) * D_ + sc8;

    auto stage = [&](int bi, int k0) {
#pragma unroll
      for (int p = 0; p < 2; p++) {
        gload_lds16(ag + (size_t)(64 * p) * D_ + k0, At + bi * 4096 + (wid + 4 * p) * 512);
        gload_lds16(bg + (size_t)(64 * p) * D_ + k0, Bt + bi * 4096 + (wid + 4 * p) * 512);
      }
    };

    stage(0, 0);
    for (int k0 = 0; k0 < D_; k0 += 32) {
      const int cur = (k0 >> 5) & 1;
      __syncthreads();                       // drains vmcnt: buf[cur] ready
      if (k0 + 32 < D_) stage(cur ^ 1, k0 + 32);

      bf16x8 af[4], bfr[4];
#pragma unroll
      for (int m = 0; m < 4; m++) {
        const int row = wr + m * 16 + l15;
        af[m] = *(const bf16x8*)(At + cur * 4096 + row * 32 + (lg ^ (l15 & 3)) * 8);
      }
#pragma unroll
      for (int n = 0; n < 4; n++) {
        const int row = wc + n * 16 + l15;
        bfr[n] = *(const bf16x8*)(Bt + cur * 4096 + row * 32 + (lg ^ (l15 & 3)) * 8);
      }
#pragma unroll
      for (int m = 0; m < 4; m++)
#pragma unroll
        for (int n = 0; n < 4; n++)
          acc[m][n] = __builtin_amdgcn_mfma_f32_16x16x32_bf16(af[m], bfr[n], acc[m][n], 0, 0, 0);
    }

    if (z == 2) {
      // V written TRANSPOSED per head: VTg[((b*12+h)*64+d)][n]
#pragma unroll
      for (int n = 0; n < 4; n++) {
        const int col = n0 + wc + n * 16 + l15;
        const float bval = bias[col];
        const int hh = col >> 6, dd = col & 63;
#pragma unroll
        for (int m = 0; m < 4; m++) {
          const int row = m0 + wr + m * 16 + 4 * lg;
          const int bb = row >> 10, nn = row & 1023;
          short4_t o;
#pragma unroll
          for (int r = 0; r < 4; r++) o[r] = f2bf(acc[m][n][r] + bval);
          *(short4_t*)&C[(((size_t)bb * H_ + hh) * HD_ + dd) * N_ + nn] = o;
        }
      }
    } else {
#pragma unroll
      for (int n = 0; n < 4; n++) {
        const int col = n0 + wc + n * 16 + l15;
        const float bval = bias[col];
#pragma unroll
        for (int m = 0; m < 4; m++) {
#pragma unroll
          for (int r = 0; r < 4; r++) {
            const int row = m0 + wr + m * 16 + 4 * lg + r;
            C[(size_t)row * D_ + col] = f2bf((acc[m][n][r] + bval) * alpha);
          }
        }
      }
    }
  } else {
    // ================= madj: fused mask/beta/log2e, 32x32 S^T C-fragment order =================
    const int j = bid - 1152;
    const int b = j >> 8;
    const int rr = j & 255;
    const int qt64 = rr >> 4, kt = rr & 15;   // 64-q-row slab
    const float b2 = beta_p[0] * LOG2E;
    const float MASKV = -9.0e15f * LOG2E;

    float* Lt = (float*)smem;                  // [64][68]
    {
      const int row = tid >> 2, cs = (tid & 3) * 16;
      const float* ap = adj + ((size_t)b * N_ + qt64 * 64 + row) * (size_t)N_ + kt * 64 + cs;
#pragma unroll
      for (int jj = 0; jj < 4; jj++)
        *(float4*)(Lt + row * 68 + cs + 4 * jj) = *(const float4*)(ap + 4 * jj);
    }
    __syncthreads();

    const int a = tid >> 1, cb = tid & 1;
    const int lane_att = a & 63;
    const int l31 = lane_att & 31, hia = lane_att >> 5;
    const int q_local = 32 * (a >> 6) + l31;

    short vals[16];
#pragma unroll
    for (int t = 0; t < 4; t++) {
      float4 a4 = *(const float4*)(Lt + q_local * 68 + 32 * cb + 8 * t + 4 * hia);
      float av[4] = {a4.x, a4.y, a4.z, a4.w};
#pragma unroll
      for (int r2 = 0; r2 < 4; r2++) {
        float av_ = av[r2];
        vals[4 * t + r2] = f2bf((av_ > 0.f) ? b2 * av_ : MASKV);
      }
    }
    short* o = madjF + ((size_t)((b * 8 + (qt64 >> 1)) * 16 + kt)) * 8192 +
               (qt64 & 1) * 4096 + tid * 16;
    bf16x8 lo, hi;
#pragma unroll
    for (int jj = 0; jj < 8; jj++) { lo[jj] = vals[jj]; hi[jj] = vals[8 + jj]; }
    *(bf16x8*)o = lo;
    *(bf16x8*)(o + 8) = hi;
  }
}

// ---- attn helper macros (flat code, constant-indexed arrays only) ----
// QK half: 4 chained MFMAs, C-init from two bf16x8 madj fragments
#define QK_HALF(SREG, K0, ROWOFF, MJA, MJB)                                    \
  {                                                                            \
    f32x16 c_;                                                                 \
    _Pragma("unroll") for (int r_ = 0; r_ < 8; r_++) c_[r_] = bf2f(MJA[r_]);   \
    _Pragma("unroll") for (int r_ = 0; r_ < 8; r_++) c_[8 + r_] = bf2f(MJB[r_]);\
    _Pragma("unroll") for (int s_ = 0; s_ < 4; s_++) {                         \
      bf16x8 kf_ = *(const bf16x8*)((K0) + ((ROWOFF) + l31) * 64 +             \
                                    (((2 * s_ + hi) ^ swz) * 8));              \
      c_ = __builtin_amdgcn_mfma_f32_32x32x16_bf16(kf_, qf[s_], c_, 0, 0, 0);  \
    }                                                                          \
    SREG = c_;                                                                 \
  }

// pack half: 16 exp2 + row-sum contrib + 8 cvtpk + 4 permlane -> FW[OFF..OFF+7]
#define PACK_HALF(SREG, FW, OFF)                                               \
  {                                                                            \
    _Pragma("unroll") for (int r_ = 0; r_ < 16; r_++) {                        \
      SREG[r_] = __builtin_exp2f(SREG[r_]); ps += SREG[r_];                    \
    }                                                                          \
    u32 wv_[8];                                                                \
    _Pragma("unroll") for (int c_ = 0; c_ < 8; c_++)                           \
      wv_[c_] = cvtpk(SREG[2 * c_], SREG[2 * c_ + 1]);                         \
    pl32swap(wv_[0], wv_[2]); FW[(OFF) + 0] = wv_[0]; FW[(OFF) + 2] = wv_[2];  \
    pl32swap(wv_[1], wv_[3]); FW[(OFF) + 1] = wv_[1]; FW[(OFF) + 3] = wv_[3];  \
    pl32swap(wv_[4], wv_[6]); FW[(OFF) + 4] = wv_[4]; FW[(OFF) + 6] = wv_[6];  \
    pl32swap(wv_[5], wv_[7]); FW[(OFF) + 5] = wv_[5]; FW[(OFF) + 7] = wv_[7];  \
  }

// PV half: 2 k-slices (KS0, KS0+1), 4 MFMAs into acc0/acc1
#define PV_HALF(FW, V0, KS0)                                                   \
  _Pragma("unroll") for (int ks_ = (KS0); ks_ < (KS0) + 2; ks_++) {            \
    union { u32 u[4]; bf16x8 v; } pu_;                                         \
    pu_.u[0] = FW[4 * ks_];     pu_.u[1] = FW[4 * ks_ + 1];                    \
    pu_.u[2] = FW[4 * ks_ + 2]; pu_.u[3] = FW[4 * ks_ + 3];                    \
    bf16x8 vf0_ = *(const bf16x8*)((V0) + l31 * 64 + (((2 * ks_ + hi) ^ swz) * 8)); \
    bf16x8 vf1_ = *(const bf16x8*)((V0) + (32 + l31) * 64 + (((2 * ks_ + hi) ^ swz) * 8)); \
    acc0 = __builtin_amdgcn_mfma_f32_32x32x16_bf16(vf0_, pu_.v, acc0, 0, 0, 0);\
    acc1 = __builtin_amdgcn_mfma_f32_32x32x16_bf16(vf1_, pu_.v, acc1, 0, 0, 0);\
  }

// ---------------- flash attention: 32x32 MFMA, no-max softmax, 1-tile-lookbehind PV -------
// Per tile t: QK(t) [MFMA] + PV(t-1) [MFMA, indep] + pack(t) [VALU] interleave.
// Cross-tile state: packed P fragments fwP[16] (u32) only. K 2-buf, V 3-buf in LDS.
// l_ accumulates per-lane half-row sums; single cross-half shfl reduce at the end.
__global__ __launch_bounds__(256, 3)
void attn_kernel(const short* __restrict__ QKV, const short* __restrict__ madjF,
                 float* __restrict__ out) {
  const short* Qb = QKV;
  const short* Kb = QKV + (size_t)(B_ * N_) * D_;
  const short* VTg = QKV + 2 * (size_t)(B_ * N_) * D_;   // per-head transposed V

  // 768 blocks = 8 XCD x 96; batch b pinned to XCD b
  const int wg = blockIdx.x;
  const int b = wg & 7;
  const int rem = wg >> 3;        // 0..95
  const int h = rem >> 3;         // 0..11
  const int qt = rem & 7;         // 0..7 (128-row q tiles)

  const int tid = threadIdx.x;
  const int lane = tid & 63;
  const int w = tid >> 6;         // wave 0..3: q rows [32w, 32w+32)
  const int l31 = lane & 31;
  const int hi = lane >> 5;
  const int swz = lane & 7;       // LDS chunk swizzle key

  const int q0 = qt * 128;
  const size_t seq0 = (size_t)b * N_;
  const int hc = h * HD_;

  __shared__ short Kt[2][64][64];    // row k', phys 16B-chunk p holds logical chunk p^(k'&7)
  __shared__ short VTt[3][64][64];   // row d, same swizzle; triple-buffered

  // Q fragments: lane holds Q[q=q0+32w+l31][d = 16s + 8hi + j]
  bf16x8 qf[4];
  {
    const short* qp = Qb + (seq0 + q0 + 32 * w + l31) * (size_t)D_ + hc + 8 * hi;
#pragma unroll
    for (int s = 0; s < 4; s++) qf[s] = *(const bf16x8*)(qp + 16 * s);
  }

  f32x16 acc0 = {}, acc1 = {};     // PV acc: D[d][q], d-tiles 0,1
  float l_ = 0.f;

  // staging: each wave stages 16 rows of K and 16 rows of V^T per tile (2 DMA each)
  const int srow = 16 * w + (lane >> 3);
  const int sc8 = ((lane & 7) ^ (lane >> 3)) * 8;
  const short* kg = Kb + (seq0 + srow) * (size_t)D_ + hc + sc8;
  const short* vg = VTg + ((size_t)(b * H_ + h) * HD_ + srow) * N_ + sc8;
  const short* mg = madjF + ((size_t)(b * 8 + qt) * 16) * 8192 + (w * 64 + lane) * 32;

  bf16x8 mjc[4], mjn[4];
  u32 fwP[16], fwN[16];

  // prologue: stage tiles 0,1; full QK+pack of tile 0 (no PV yet)
  {
    gload_lds16(kg, ((short*)Kt[0]) + (size_t)w * 1024);
    gload_lds16(kg + 8 * (size_t)D_, ((short*)Kt[0]) + (size_t)w * 1024 + 512);
    gload_lds16(vg, ((short*)VTt[0]) + (size_t)w * 1024);
    gload_lds16(vg + 8 * (size_t)N_, ((short*)VTt[0]) + (size_t)w * 1024 + 512);
#pragma unroll
    for (int j = 0; j < 4; j++) mjc[j] = *(const bf16x8*)(mg + 8 * j);
    __syncthreads();
    gload_lds16(kg + (size_t)64 * D_, ((short*)Kt[1]) + (size_t)w * 1024);
    gload_lds16(kg + (size_t)72 * D_, ((short*)Kt[1]) + (size_t)w * 1024 + 512);
    gload_lds16(vg + 64, ((short*)VTt[1]) + (size_t)w * 1024);
    gload_lds16(vg + 64 + 8 * (size_t)N_, ((short*)VTt[1]) + (size_t)w * 1024 + 512);
#pragma unroll
    for (int j = 0; j < 4; j++) mjn[j] = *(const bf16x8*)(mg + 8192 + 8 * j);

    float ps = 0.f;
    f32x16 s0, s1;
    const short* K0 = (const short*)Kt[0];
    QK_HALF(s0, K0, 0, mjc[0], mjc[1]);
    PACK_HALF(s0, fwP, 0);
    QK_HALF(s1, K0, 32, mjc[2], mjc[3]);
    PACK_HALF(s1, fwP, 8);
    l_ += ps;
#pragma unroll
    for (int j = 0; j < 4; j++) mjc[j] = mjn[j];
  }

  // main loop: tiles 1..15.  QK(t) + PV(t-1) + pack(t).
  int vprev = 0;   // (t-1)%3
  int vstage = 2;  // (t+1)%3
  for (int t = 1; t < 16; t++) {
    __syncthreads();                 // tile t staged; prev-tile LDS reads done
    if (t < 15) {
      const int k0 = (t + 1) * 64;
      gload_lds16(kg + (size_t)k0 * D_, ((short*)Kt[(t + 1) & 1]) + (size_t)w * 1024);
      gload_lds16(kg + (size_t)(k0 + 8) * D_, ((short*)Kt[(t + 1) & 1]) + (size_t)w * 1024 + 512);
      gload_lds16(vg + k0, ((short*)VTt[vstage]) + (size_t)w * 1024);
      gload_lds16(vg + k0 + 8 * (size_t)N_, ((short*)VTt[vstage]) + (size_t)w * 1024 + 512);
#pragma unroll
      for (int j = 0; j < 4; j++)
        mjn[j] = *(const bf16x8*)(mg + (size_t)(t + 1) * 8192 + 8 * j);
    }

    const short* K0 = (const short*)Kt[t & 1];
    const short* V0 = (const short*)VTt[vprev];
    float ps = 0.f;
    f32x16 s0, s1;

    QK_HALF(s0, K0, 0, mjc[0], mjc[1]);   // MFMA chain A
    PV_HALF(fwP, V0, 0);                  // MFMA, independent of A — fills pipe
    PACK_HALF(s0, fwN, 0);                // VALU, dep A — overlaps PV MFMAs
    QK_HALF(s1, K0, 32, mjc[2], mjc[3]);  // MFMA chain B
    PV_HALF(fwP, V0, 2);                  // MFMA, independent
    PACK_HALF(s1, fwN, 8);                // VALU, dep B
    l_ += ps;

#pragma unroll
    for (int i = 0; i < 16; i++) fwP[i] = fwN[i];
#pragma unroll
    for (int j = 0; j < 4; j++) mjc[j] = mjn[j];
    vprev = (vprev == 2) ? 0 : vprev + 1;
    vstage = (vstage == 2) ? 0 : vstage + 1;
  }

  // tail: PV of tile 15 (V buffer = 15%3 = vprev after loop)
  {
    const short* V0 = (const short*)VTt[vprev];
    PV_HALF(fwP, V0, 0);
    PV_HALF(fwP, V0, 2);
  }

  // cross-half reduce of l (each lane held only its hi-half k-sums), then normalize
  l_ += __shfl_xor(l_, 32);
  const float invl = 1.f / l_;
  float* orow = out + (seq0 + q0 + 32 * w + l31) * (size_t)D_ + hc;
#pragma unroll
  for (int t = 0; t < 4; t++) {
    float4 o0, o1;
    o0.x = acc0[4 * t] * invl;     o0.y = acc0[4 * t + 1] * invl;
    o0.z = acc0[4 * t + 2] * invl; o0.w = acc0[4 * t + 3] * invl;
    o1.x = acc1[4 * t] * invl;     o1.y = acc1[4 * t + 1] * invl;
    o1.z = acc1[4 * t + 2] * invl; o1.w = acc1[4 * t + 3] * invl;
    *(float4*)(orow + 8 * t + 4 * hi) = o0;
    *(float4*)(orow + 8 * t + 4 * hi + 32) = o1;
  }
}

extern "C" void kernel_launch(void* const* d_in, const int* in_sizes, int n_in,
                              void* d_out, int out_size, void* d_ws, size_t ws_size,
                              hipStream_t stream) {
  const float* X    = (const float*)d_in[0];
  const float* adj  = (const float*)d_in[1];
  const float* Wq   = (const float*)d_in[2];
  const float* bq   = (const float*)d_in[3];
  const float* Wk   = (const float*)d_in[4];
  const float* bk   = (const float*)d_in[5];
  const float* Wv   = (const float*)d_in[6];
  const float* bv   = (const float*)d_in[7];
  const float* beta = (const float*)d_in[8];
  float* out = (float*)d_out;

  // workspace (shorts): Xb | Wt3 | QKV | madjF  (V slab of QKV holds per-head transposed V)
  short* Xb    = (short*)d_ws;
  short* Wt3   = Xb + (size_t)(B_ * N_) * D_;
  short* QKV   = Wt3 + 3 * (size_t)D_ * D_;
  short* madjF = QKV + 3 * (size_t)(B_ * N_) * D_;

  cvt_kernel<<<dim3(4800), 256, 0, stream>>>(X, Xb, Wq, Wk, Wv, Wt3);
  gemm_madj_kernel<<<dim3(3200), 256, 0, stream>>>(Xb, Wt3, bq, bk, bv, QKV, adj, beta, madjF);
  attn_kernel<<<dim3(768), 256, 0, stream>>>(QKV, madjF, out);
}